// Round 7
// baseline (326.850 us; speedup 1.0000x reference)
//
#include <hip/hip_runtime.h>
#include <hip/hip_bf16.h>
#include <stdint.h>

// Problem constants
#define Bn 4
#define Cn 1024
#define Tn 2048
#define Hn 16
#define Gn 32
// attention scale: softmax(q.k * 0.125). 0.125*log2(e) folded into Q at the
// QKV epilogue so attention computes P = exp2(S) directly (no max-subtraction:
// GroupNormed inputs bound |S| far below f32 exp2 range; l is summed from the
// same bf16-truncated P so truncation bias cancels in the final divide).
#define SCALE_Q 0.18033688f   // 0.125 * 1.4426950408889634

typedef short short8  __attribute__((ext_vector_type(8)));   // 8 bf16 (x32 A/B)
typedef short short4_t __attribute__((ext_vector_type(4)));  // 4 bf16
typedef float float4_t __attribute__((ext_vector_type(4)));  // C/D frag
typedef unsigned int uint2_t __attribute__((ext_vector_type(2)));

__device__ __forceinline__ short f2bf(float f) {
    uint32_t u = __float_as_uint(f);
    uint32_t r = (u + 0x7FFFu + ((u >> 16) & 1u)) >> 16;
    return (short)r;
}

__device__ __forceinline__ float exp2_fast(float x) {
#if __has_builtin(__builtin_amdgcn_exp2f)
    return __builtin_amdgcn_exp2f(x);
#else
    return exp2f(x);
#endif
}

__device__ __forceinline__ uint32_t pack_bf16_trunc(float lo, float hi) {
#if __has_builtin(__builtin_amdgcn_perm)
    return __builtin_amdgcn_perm(__float_as_uint(hi), __float_as_uint(lo), 0x07060302u);
#else
    return (__float_as_uint(lo) >> 16) | (__float_as_uint(hi) & 0xFFFF0000u);
#endif
}

// gfx950 cross-lane half swaps. swap32: x'[32:63]<->y[0:31].
// swap16: x'[16:31]<->y[0:15], x'[48:63]<->y[32:47]. l15 preserved by both.
__device__ __forceinline__ void permswap32(uint32_t& x, uint32_t& y) {
#if __has_builtin(__builtin_amdgcn_permlane32_swap)
    uint2_t r = __builtin_amdgcn_permlane32_swap(x, y, false, false);
    x = r[0]; y = r[1];
#else
    asm volatile("v_permlane32_swap_b32 %0, %1" : "+v"(x), "+v"(y));
#endif
}
__device__ __forceinline__ void permswap16(uint32_t& x, uint32_t& y) {
#if __has_builtin(__builtin_amdgcn_permlane16_swap)
    uint2_t r = __builtin_amdgcn_permlane16_swap(x, y, false, false);
    x = r[0]; y = r[1];
#else
    asm volatile("v_permlane16_swap_b32 %0, %1" : "+v"(x), "+v"(y));
#endif
}

// global -> LDS direct (16B per lane). LDS dest must be wave-uniform + lane*16.
#define GLL16(gptr, lptr)                                                      \
    __builtin_amdgcn_global_load_lds(                                          \
        (const __attribute__((address_space(1))) unsigned int*)(gptr),         \
        (__attribute__((address_space(3))) unsigned int*)(lptr), 16, 0, 0)

// ---------------------------------------------------------------- weights cvt
__global__ __launch_bounds__(256) void cvt_w(const float* __restrict__ src,
                                             short* __restrict__ dst, int n4) {
    int i = blockIdx.x * 256 + threadIdx.x;
    if (i < n4) {
        float4_t v = reinterpret_cast<const float4_t*>(src)[i];
        short4_t o;
        o[0] = f2bf(v[0]); o[1] = f2bf(v[1]); o[2] = f2bf(v[2]); o[3] = f2bf(v[3]);
        reinterpret_cast<short4_t*>(dst)[i] = o;
    }
}

// ---------------------------------------------------------------- GroupNorm
__global__ __launch_bounds__(256) void groupnorm_k(const float* __restrict__ x,
                                                   const float* __restrict__ gs,
                                                   const float* __restrict__ gb,
                                                   short* __restrict__ xnT) {
    int blk = blockIdx.x;
    int b = blk >> 5, g = blk & 31;
    const float* base = x + ((size_t)(b * Cn + g * 32)) * Tn;
    int tid = threadIdx.x;

    float s = 0.f, ss = 0.f;
    const float4_t* b4 = reinterpret_cast<const float4_t*>(base);
    for (int i = tid; i < 16384; i += 256) {
        float4_t v = b4[i];
        s  += v[0] + v[1] + v[2] + v[3];
        ss += v[0]*v[0] + v[1]*v[1] + v[2]*v[2] + v[3]*v[3];
    }
    #pragma unroll
    for (int m = 1; m < 64; m <<= 1) { s += __shfl_xor(s, m); ss += __shfl_xor(ss, m); }
    __shared__ float red[8];
    int wave = tid >> 6;
    if ((tid & 63) == 0) { red[wave * 2] = s; red[wave * 2 + 1] = ss; }
    __syncthreads();
    float ts  = red[0] + red[2] + red[4] + red[6];
    float tss = red[1] + red[3] + red[5] + red[7];
    float mean = ts * (1.f / 65536.f);
    float var  = tss * (1.f / 65536.f) - mean * mean;
    float rstd = rsqrtf(var + 1e-5f);

    __shared__ float tile[64][33];
    for (int t0 = 0; t0 < Tn; t0 += 64) {
        #pragma unroll
        for (int k = 0; k < 8; k++) {
            int e = tid + k * 256;
            int c = e >> 6, tt = e & 63;
            float v = base[c * Tn + t0 + tt];
            tile[tt][c] = (v - mean) * rstd * gs[g * 32 + c] + gb[g * 32 + c];
        }
        __syncthreads();
        #pragma unroll
        for (int k = 0; k < 8; k++) {
            int f = tid + k * 256;
            int tt = f >> 5, c = f & 31;
            xnT[((size_t)(b * Tn + t0 + tt)) * Cn + g * 32 + c] = f2bf(tile[tt][c]);
        }
        __syncthreads();
    }
}

// ---------------------------------------------------------------- GEMM
// R5 (kept): counted-vmcnt software pipeline (T4). stage runs TWO K-tiles
// ahead; raw s_barrier (no drain); inline-asm s_waitcnt vmcnt(8) waits only
// for the PREVIOUS tile's 8 loads while the newest 8 stay in flight across
// the barrier. Verified R5: QKV 100->77 us, FETCH/WRITE back to baseline.
// MODE 0: QKV — q rows pre-scaled by SCALE_Q, q/k transposed to [bh][t][64],
//         v natural [b][c][t]. MODE 1: proj — out = x + bias + acc.
template <int MODE>
__global__ __launch_bounds__(256) void gemm_k(const short* __restrict__ W,
                                              const short* __restrict__ Bm,
                                              const float* __restrict__ bias,
                                              const float* __restrict__ xres,
                                              short* __restrict__ qkT,
                                              short* __restrict__ vbuf,
                                              float* __restrict__ outp) {
    constexpr int K = 1024;
    constexpr int NT = K / 64;
    __shared__ short As[2][128 * 64];
    __shared__ short Bs[2][128 * 64];

    int m0 = blockIdx.x * 128, n0 = blockIdx.y * 128, b = blockIdx.z;
    int tid = threadIdx.x;
    int wave = tid >> 6, lane = tid & 63, quad = lane >> 4, l15 = lane & 15;
    int wm = wave >> 1, wn = wave & 1;
    const short* Ab = W + (size_t)m0 * K;
    const short* Bb = Bm + ((size_t)b * Tn + n0) * K;

    float4_t acc[4][4];
    float4_t z = {0.f, 0.f, 0.f, 0.f};
    #pragma unroll
    for (int i = 0; i < 4; i++)
        #pragma unroll
        for (int j = 0; j < 4; j++) acc[i][j] = z;

    int sw = l15 & 7;   // read-side swizzle key

    // per-thread staging geometry (swizzled global column, linear LDS dest)
    // 8 GLL16 per wave per tile (4 A + 4 B) -> vmcnt granularity 8/tile.
    auto stage = [&](int buf, int k0) {
        #pragma unroll
        for (int r = 0; r < 4; r++) {
            int cid = r * 256 + tid;           // 1024 16B-chunks per array
            int row = cid >> 3, j = cid & 7;
            int ch = j ^ (row & 7);            // swizzled global column
            GLL16(Ab + (size_t)row * K + k0 + ch * 8, &As[buf][cid * 8]);
            GLL16(Bb + (size_t)row * K + k0 + ch * 8, &Bs[buf][cid * 8]);
        }
    };

    // prologue: tiles 0 and 1 in flight; wait for tile 0 only (oldest 8)
    stage(0, 0);
    stage(1, 64);
    __builtin_amdgcn_sched_barrier(0);
    asm volatile("s_waitcnt vmcnt(8)" ::: "memory");
    __builtin_amdgcn_sched_barrier(0);
    __builtin_amdgcn_s_barrier();
    __builtin_amdgcn_sched_barrier(0);

    for (int it = 0; it < NT; ++it) {
        int cur = it & 1;
        #pragma unroll
        for (int kk = 0; kk < 2; kk++) {
            short8 af[4], bfg[4];
            #pragma unroll
            for (int mi = 0; mi < 4; mi++)
                af[mi] = *reinterpret_cast<const short8*>(
                    &As[cur][(wm * 64 + mi * 16 + l15) * 64 + ((4 * kk + quad) ^ sw) * 8]);
            #pragma unroll
            for (int ni = 0; ni < 4; ni++)
                bfg[ni] = *reinterpret_cast<const short8*>(
                    &Bs[cur][(wn * 64 + ni * 16 + l15) * 64 + ((4 * kk + quad) ^ sw) * 8]);
            #pragma unroll
            for (int mi = 0; mi < 4; mi++)
                #pragma unroll
                for (int ni = 0; ni < 4; ni++)
                    acc[mi][ni] = __builtin_amdgcn_mfma_f32_16x16x32_bf16(
                        af[mi], bfg[ni], acc[mi][ni], 0, 0, 0);
        }
        __builtin_amdgcn_sched_barrier(0);
        __builtin_amdgcn_s_barrier();            // all waves done reading buf[cur]
        __builtin_amdgcn_sched_barrier(0);
        if (it + 2 < NT) stage(cur, (it + 2) * 64);   // overwrite freed buffer
        __builtin_amdgcn_sched_barrier(0);
        if (it + 2 < NT) {
            // own outstanding: (it+1)'s 8 + (it+2)'s 8; wait oldest 8 -> it+1 landed
            asm volatile("s_waitcnt vmcnt(8)" ::: "memory");
        } else if (it + 1 < NT) {
            asm volatile("s_waitcnt vmcnt(0)" ::: "memory");
        }
        __builtin_amdgcn_sched_barrier(0);
        __builtin_amdgcn_s_barrier();            // cross-wave: it+1 resident
        __builtin_amdgcn_sched_barrier(0);
    }

    if (MODE == 0) {
        #pragma unroll
        for (int mi = 0; mi < 4; mi++) {
            int mrow = m0 + wm * 64 + mi * 16 + quad * 4;
            #pragma unroll
            for (int ni = 0; ni < 4; ni++) {
                int t = n0 + wn * 64 + ni * 16 + l15;
                if (mrow < 2048) {
                    int hh = mrow >> 6, ch = mrow & 63;
                    float sc = (mrow < 1024) ? SCALE_Q : 1.0f;
                    short4_t pk;
                    #pragma unroll
                    for (int r = 0; r < 4; r++)
                        pk[r] = f2bf((acc[mi][ni][r] + bias[mrow + r]) * sc);
                    *reinterpret_cast<short4_t*>(
                        &qkT[(((size_t)b * 32 + hh) * Tn + t) * 64 + ch]) = pk;
                } else {
                    int c = mrow - 2048;
                    #pragma unroll
                    for (int r = 0; r < 4; r++)
                        vbuf[((size_t)b * Cn + c + r) * Tn + t] =
                            f2bf(acc[mi][ni][r] + bias[mrow + r]);
                }
            }
        }
    } else {
        #pragma unroll
        for (int mi = 0; mi < 4; mi++) {
            int mrow = m0 + wm * 64 + mi * 16 + quad * 4;
            #pragma unroll
            for (int ni = 0; ni < 4; ni++) {
                int t = n0 + wn * 64 + ni * 16 + l15;
                #pragma unroll
                for (int r = 0; r < 4; r++) {
                    size_t idx = ((size_t)b * Cn + mrow + r) * Tn + t;
                    outp[idx] = xres[idx] + bias[mrow + r] + acc[mi][ni][r];
                }
            }
        }
    }
}

// ---------------------------------------------------------------- attention
// R7: back to R5 shape (nt=2, 512 thr, grid(8,64), 2 blocks/CU) — R6 proved
// LDS/HBM staging volume is NOT the limiter (halving both changed nothing);
// the limiter is serialized MFMA<->VALU phases (R5: 44+50=94% busy = sum,
// not max: all waves lockstep through QK-MFMA then exp2). Three changes:
// 1) PHASE-STAGGER: odd waves process the two 32-s pr-blocks in reverse
//    order (pr = p2 ^ (wave&1)) -> at any instant half the waves feed the
//    MFMA pipe while half run exp2/pack on the VALU. pr-blocks accumulate
//    independently into acc (commutative) — order is correctness-neutral.
// 2) GLL16 staging, both-sides XOR swizzle (gemm_k's proven pattern):
//    linear LDS dest + pre-swizzled global column + XOR on read side.
//    Kills reg round-trip + ds_writes + addressing VALU; LDS 36->32 KB.
// 3) Counted-vmcnt pipeline (T4, gemm-proven): stage 2 tiles ahead, raw
//    s_barrier, vmcnt(2) mid-loop (never 0). 2 GLL16/thread/tile.
__global__ __launch_bounds__(512, 4) void attn_k(const short* __restrict__ qkT,
                                                 const short* __restrict__ vbuf,
                                                 short* __restrict__ aT) {
    constexpr int NT = Tn / 64;
    __shared__ short ks[2][64 * 64];   // [s][ch], XOR-swizzled chunks
    __shared__ short vs[2][64 * 64];   // [ch][s], XOR-swizzled chunks
    int bh = blockIdx.y; int b = bh >> 4, h = bh & 15;
    int t0 = blockIdx.x * 256;
    int tid = threadIdx.x;
    int wave = tid >> 6, lane = tid & 63, quad = lane >> 4, l15 = lane & 15;
    const short* qb = qkT + (((size_t)b * 32 + h) * Tn) * 64;
    const short* kb = qkT + (((size_t)b * 32 + 16 + h) * Tn) * 64;
    const short* vb = vbuf + ((size_t)b * Cn + h * 64) * Tn;
    int tw = t0 + wave * 32;
    int rsw = l15 & 7;                 // read-side swizzle key (row&7)

    // Q B-frags for 2 q-subtiles (global, once)
    short8 qf[2][2];
    #pragma unroll
    for (int tni = 0; tni < 2; tni++)
        #pragma unroll
        for (int kk = 0; kk < 2; kk++)
            qf[tni][kk] = *reinterpret_cast<const short8*>(
                qb + ((size_t)(tw + tni * 16 + l15)) * 64 + kk * 32 + quad * 8);

    short8 ones;
    #pragma unroll
    for (int i = 0; i < 8; i++) ones[i] = (short)0x3F80;   // bf16 1.0

    float4_t z = {0.f, 0.f, 0.f, 0.f};
    float4_t acc[2][4], lacc[2];
    #pragma unroll
    for (int i = 0; i < 2; i++) {
        lacc[i] = z;
        #pragma unroll
        for (int j = 0; j < 4; j++) acc[i][j] = z;
    }

    // staging: 512 threads x one 16B chunk per array per tile.
    // LDS chunk (row=tid>>3, j=tid&7) holds global column-chunk j^(row&7).
    int srow = tid >> 3, sj = tid & 7;
    int ssw = (sj ^ (srow & 7)) * 8;   // swizzled source element offset
    const short* kgp = kb + (size_t)srow * 64 + ssw;   // +4096 per tile
    const short* vgp = vb + (size_t)srow * Tn + ssw;   // +64 per tile

    auto stageKV = [&](int buf, int t) {
        GLL16(kgp + (size_t)t * 4096, &ks[buf][tid * 8]);
        GLL16(vgp + (size_t)t * 64,   &vs[buf][tid * 8]);
    };

    // prologue: tiles 0,1 in flight; wait oldest 2 (tile 0; also drains qf)
    stageKV(0, 0);
    stageKV(1, 1);
    __builtin_amdgcn_sched_barrier(0);
    asm volatile("s_waitcnt vmcnt(2)" ::: "memory");
    __builtin_amdgcn_sched_barrier(0);
    __builtin_amdgcn_s_barrier();
    __builtin_amdgcn_sched_barrier(0);

    int prs = wave & 1;                // stagger: odd waves reverse pr order

    for (int it = 0; it < NT; ++it) {
        int cur = it & 1;
        #pragma unroll
        for (int p2 = 0; p2 < 2; p2++) {
            int pr = p2 ^ prs;                  // 32-s pair block
            uint32_t pk[2][2][2];               // [half][tni][dword], bf16 P
            #pragma unroll
            for (int half = 0; half < 2; half++) {
                int smi = pr * 2 + half;
                // S^T: rows s = smi*16 + quad*4 + r, cols t = tni*16 + l15
                float4_t sa[2] = {z, z};
                __builtin_amdgcn_s_setprio(1);
                #pragma unroll
                for (int kk = 0; kk < 2; kk++) {
                    short8 kf = *reinterpret_cast<const short8*>(
                        &ks[cur][(smi * 16 + l15) * 64 + ((kk * 4 + quad) ^ rsw) * 8]);
                    #pragma unroll
                    for (int tni = 0; tni < 2; tni++)
                        sa[tni] = __builtin_amdgcn_mfma_f32_16x16x32_bf16(
                            kf, qf[tni][kk], sa[tni], 0, 0, 0);
                }
                __builtin_amdgcn_s_setprio(0);
                #pragma unroll
                for (int tni = 0; tni < 2; tni++) {
                    float p0 = exp2_fast(sa[tni][0]);
                    float p1 = exp2_fast(sa[tni][1]);
                    float p2v = exp2_fast(sa[tni][2]);
                    float p3 = exp2_fast(sa[tni][3]);
                    pk[half][tni][0] = pack_bf16_trunc(p0, p1);
                    pk[half][tni][1] = pack_bf16_trunc(p2v, p3);
                }
            }
            // V B-frags for x32 PV: lane wants V[ch=ci*16+l15][s=pr*32+quad*8..+7]
            short8 vf[4];
            #pragma unroll
            for (int ci = 0; ci < 4; ci++)
                vf[ci] = *reinterpret_cast<const short8*>(
                    &vs[cur][(ci * 16 + l15) * 64 + ((pr * 4 + quad) ^ rsw) * 8]);
            // merge the two 16-s halves into x32 A-layout:
            // (d0,d2) = swap16(swap32(a0,b0)); (d1,d3) = swap16(swap32(a1,b1))
            #pragma unroll
            for (int tni = 0; tni < 2; tni++) {
                uint32_t x0 = pk[0][tni][0], y0 = pk[1][tni][0];
                permswap32(x0, y0); permswap16(x0, y0);   // x0=d0, y0=d2
                uint32_t x1 = pk[0][tni][1], y1 = pk[1][tni][1];
                permswap32(x1, y1); permswap16(x1, y1);   // x1=d1, y1=d3
                uint4 afu = {x0, x1, y0, y1};
                short8 af = *reinterpret_cast<short8*>(&afu);
                __builtin_amdgcn_s_setprio(1);
                lacc[tni] = __builtin_amdgcn_mfma_f32_16x16x32_bf16(
                    af, ones, lacc[tni], 0, 0, 0);
                #pragma unroll
                for (int ci = 0; ci < 4; ci++)
                    acc[tni][ci] = __builtin_amdgcn_mfma_f32_16x16x32_bf16(
                        af, vf[ci], acc[tni][ci], 0, 0, 0);
                __builtin_amdgcn_s_setprio(0);
            }
        }

        // counted-vmcnt pipeline epilogue of the iteration
        __builtin_amdgcn_sched_barrier(0);
        __builtin_amdgcn_s_barrier();            // all waves done reading buf[cur]
        __builtin_amdgcn_sched_barrier(0);
        if (it + 2 < NT) stageKV(cur, it + 2);   // overwrite freed buffer
        __builtin_amdgcn_sched_barrier(0);
        if (it + 2 < NT) {
            // outstanding: (it+1)'s 2 + (it+2)'s 2; wait oldest 2 -> it+1 landed
            asm volatile("s_waitcnt vmcnt(2)" ::: "memory");
        } else if (it + 1 < NT) {
            asm volatile("s_waitcnt vmcnt(0)" ::: "memory");
        }
        __builtin_amdgcn_sched_barrier(0);
        __builtin_amdgcn_s_barrier();            // cross-wave: it+1 resident
        __builtin_amdgcn_sched_barrier(0);
    }

    // epilogue: aT[b][t][h*64+ch] = acc / l ; lacc rows are t = quad*4+r,
    // same layout as acc rows — no cross-lane reduction needed.
    #pragma unroll
    for (int tni = 0; tni < 2; tni++) {
        #pragma unroll
        for (int r = 0; r < 4; r++) {
            float rl = 1.0f / lacc[tni][r];
            int t = tw + tni * 16 + quad * 4 + r;
            #pragma unroll
            for (int ci = 0; ci < 4; ci++) {
                int ch = ci * 16 + l15;
                aT[((size_t)b * Tn + t) * Cn + h * 64 + ch] =
                    f2bf(acc[tni][ci][r] * rl);
            }
        }
    }
}

// ---------------------------------------------------------------- launch
extern "C" void kernel_launch(void* const* d_in, const int* in_sizes, int n_in,
                              void* d_out, int out_size, void* d_ws, size_t ws_size,
                              hipStream_t stream) {
    const float* x     = (const float*)d_in[0];
    const float* gs    = (const float*)d_in[1];
    const float* gb    = (const float*)d_in[2];
    const float* qkvw  = (const float*)d_in[3];
    const float* qkvb  = (const float*)d_in[4];
    const float* projw = (const float*)d_in[5];
    const float* projb = (const float*)d_in[6];
    float* out = (float*)d_out;

    char* ws = (char*)d_ws;
    short* wqkv  = (short*)(ws + 0);          //  6 MB  [3072][1024] bf16
    short* wproj = (short*)(ws + 6291456);    //  2 MB  [1024][1024] bf16
    short* xnT   = (short*)(ws + 8388608);    // 16 MB  [b][t][c] bf16
    short* aT    = (short*)(ws + 8388608);    // aliases xnT (dead after QKV GEMM)
    short* qkT   = (short*)(ws + 25165824);   // 32 MB  [b][32][t][64] bf16
    short* vbuf  = (short*)(ws + 58720256);   // 16 MB  [b][c][t] bf16

    cvt_w<<<dim3(3072), dim3(256), 0, stream>>>(qkvw, wqkv, 786432);
    cvt_w<<<dim3(1024), dim3(256), 0, stream>>>(projw, wproj, 262144);
    groupnorm_k<<<dim3(Bn * Gn), dim3(256), 0, stream>>>(x, gs, gb, xnT);
    gemm_k<0><<<dim3(24, 16, 4), dim3(256), 0, stream>>>(wqkv, xnT, qkvb, nullptr,
                                                         qkT, vbuf, nullptr);
    attn_k<<<dim3(8, 64), dim3(512), 0, stream>>>(qkT, vbuf, aT);
    gemm_k<1><<<dim3(8, 16, 4), dim3(256), 0, stream>>>(wproj, aT, projb, x,
                                                        nullptr, nullptr, out);
}

// Round 8
// 272.177 us; speedup vs baseline: 1.2009x; 1.2009x over previous
//
#include <hip/hip_runtime.h>
#include <hip/hip_bf16.h>
#include <stdint.h>

// Problem constants
#define Bn 4
#define Cn 1024
#define Tn 2048
#define Hn 16
#define Gn 32
// attention scale: softmax(q.k * 0.125). 0.125*log2(e) folded into Q at the
// QKV epilogue so attention computes P = exp2(S) directly (no max-subtraction:
// GroupNormed inputs bound |S| far below f32 exp2 range; l is summed from the
// same bf16-truncated P so truncation bias cancels in the final divide).
#define SCALE_Q 0.18033688f   // 0.125 * 1.4426950408889634

typedef short short8  __attribute__((ext_vector_type(8)));   // 8 bf16 (x32 A/B)
typedef short short4_t __attribute__((ext_vector_type(4)));  // 4 bf16
typedef float float4_t __attribute__((ext_vector_type(4)));  // C/D frag
typedef unsigned int uint2_t __attribute__((ext_vector_type(2)));

__device__ __forceinline__ short f2bf(float f) {
    uint32_t u = __float_as_uint(f);
    uint32_t r = (u + 0x7FFFu + ((u >> 16) & 1u)) >> 16;
    return (short)r;
}

__device__ __forceinline__ float exp2_fast(float x) {
#if __has_builtin(__builtin_amdgcn_exp2f)
    return __builtin_amdgcn_exp2f(x);
#else
    return exp2f(x);
#endif
}

__device__ __forceinline__ uint32_t pack_bf16_trunc(float lo, float hi) {
#if __has_builtin(__builtin_amdgcn_perm)
    return __builtin_amdgcn_perm(__float_as_uint(hi), __float_as_uint(lo), 0x07060302u);
#else
    return (__float_as_uint(lo) >> 16) | (__float_as_uint(hi) & 0xFFFF0000u);
#endif
}

// gfx950 cross-lane half swaps. swap32: x'[32:63]<->y[0:31].
// swap16: x'[16:31]<->y[0:15], x'[48:63]<->y[32:47]. l15 preserved by both.
__device__ __forceinline__ void permswap32(uint32_t& x, uint32_t& y) {
#if __has_builtin(__builtin_amdgcn_permlane32_swap)
    uint2_t r = __builtin_amdgcn_permlane32_swap(x, y, false, false);
    x = r[0]; y = r[1];
#else
    asm volatile("v_permlane32_swap_b32 %0, %1" : "+v"(x), "+v"(y));
#endif
}
__device__ __forceinline__ void permswap16(uint32_t& x, uint32_t& y) {
#if __has_builtin(__builtin_amdgcn_permlane16_swap)
    uint2_t r = __builtin_amdgcn_permlane16_swap(x, y, false, false);
    x = r[0]; y = r[1];
#else
    asm volatile("v_permlane16_swap_b32 %0, %1" : "+v"(x), "+v"(y));
#endif
}

// global -> LDS direct (16B per lane). LDS dest must be wave-uniform + lane*16.
#define GLL16(gptr, lptr)                                                      \
    __builtin_amdgcn_global_load_lds(                                          \
        (const __attribute__((address_space(1))) unsigned int*)(gptr),         \
        (__attribute__((address_space(3))) unsigned int*)(lptr), 16, 0, 0)

// ---------------------------------------------------------------- weights cvt
// merged: wqkv (786432 float4) and wproj (262144 float4) are contiguous in ws.
__global__ __launch_bounds__(256) void cvt_w2(const float* __restrict__ srcA,
                                              const float* __restrict__ srcB,
                                              short* __restrict__ dst) {
    int i = blockIdx.x * 256 + threadIdx.x;
    float4_t v = (i < 786432)
        ? reinterpret_cast<const float4_t*>(srcA)[i]
        : reinterpret_cast<const float4_t*>(srcB)[i - 786432];
    short4_t o;
    o[0] = f2bf(v[0]); o[1] = f2bf(v[1]); o[2] = f2bf(v[2]); o[3] = f2bf(v[3]);
    reinterpret_cast<short4_t*>(dst)[i] = o;
}

// ---------------------------------------------------------------- GroupNorm
// R8: split into two FULL-GPU passes. The old single kernel ran 128 blocks
// (half the CUs idle) and serialized stats+transpose: prime suspect for the
// ~125 us of per-iter time not in the top-5. Pass A: 1024 blocks compute
// per-slice partial sums. Pass B: 1024 blocks reduce 8 partials (16 floats)
// and normalize+transpose a 256-t slice. Partials live at the head of the
// qkT region (dead until the QKV GEMM, which runs after gn_apply).
__global__ __launch_bounds__(256) void gn_stats(const float* __restrict__ x,
                                                float* __restrict__ part) {
    int lin = blockIdx.x;              // [b:2][g:5][slice:3]
    int sl = lin & 7, g = (lin >> 3) & 31, b = lin >> 8;
    const float4_t* base = reinterpret_cast<const float4_t*>(
        x + ((size_t)(b * Cn + g * 32)) * Tn) + sl * 2048;
    int tid = threadIdx.x;
    float s = 0.f, ss = 0.f;
    #pragma unroll
    for (int k = 0; k < 8; k++) {
        float4_t v = base[tid + k * 256];
        s  += v[0] + v[1] + v[2] + v[3];
        ss += v[0]*v[0] + v[1]*v[1] + v[2]*v[2] + v[3]*v[3];
    }
    #pragma unroll
    for (int m = 1; m < 64; m <<= 1) { s += __shfl_xor(s, m); ss += __shfl_xor(ss, m); }
    __shared__ float red[8];
    int wave = tid >> 6;
    if ((tid & 63) == 0) { red[wave * 2] = s; red[wave * 2 + 1] = ss; }
    __syncthreads();
    if (tid == 0) {
        part[lin * 2]     = red[0] + red[2] + red[4] + red[6];
        part[lin * 2 + 1] = red[1] + red[3] + red[5] + red[7];
    }
}

__global__ __launch_bounds__(256) void gn_apply(const float* __restrict__ x,
                                                const float* __restrict__ gs,
                                                const float* __restrict__ gb,
                                                const float* __restrict__ part,
                                                short* __restrict__ xnT) {
    int lin = blockIdx.x;
    int sl = lin & 7, g = (lin >> 3) & 31, b = lin >> 8;
    const float* base = x + ((size_t)(b * Cn + g * 32)) * Tn;
    int tid = threadIdx.x;
    int pb = (lin >> 3) << 3;          // first slice of this (b,g)
    float ts = 0.f, tss = 0.f;
    #pragma unroll
    for (int i = 0; i < 8; i++) {
        ts  += part[(pb + i) * 2];
        tss += part[(pb + i) * 2 + 1];
    }
    float mean = ts * (1.f / 65536.f);
    float var  = tss * (1.f / 65536.f) - mean * mean;
    float rstd = rsqrtf(var + 1e-5f);

    __shared__ float tile[64][33];
    int tbase = sl * 256;
    for (int t0 = tbase; t0 < tbase + 256; t0 += 64) {
        #pragma unroll
        for (int k = 0; k < 8; k++) {
            int e = tid + k * 256;
            int c = e >> 6, tt = e & 63;
            float v = base[c * Tn + t0 + tt];
            tile[tt][c] = (v - mean) * rstd * gs[g * 32 + c] + gb[g * 32 + c];
        }
        __syncthreads();
        #pragma unroll
        for (int k = 0; k < 8; k++) {
            int f = tid + k * 256;
            int tt = f >> 5, c = f & 31;
            xnT[((size_t)(b * Tn + t0 + tt)) * Cn + g * 32 + c] = f2bf(tile[tt][c]);
        }
        __syncthreads();
    }
}

// ---------------------------------------------------------------- GEMM
// R5 (kept, proven): counted-vmcnt software pipeline (T4). stage runs TWO
// K-tiles ahead; raw s_barrier (no drain); inline-asm s_waitcnt vmcnt(8)
// waits only for the PREVIOUS tile's 8 loads while the newest 8 stay in
// flight across the barrier. Verified R5: QKV 100->77 us.
// MODE 0: QKV — q rows pre-scaled by SCALE_Q, q/k transposed to [bh][t][64],
//         v natural [b][c][t]. MODE 1: proj — out = x + bias + acc.
template <int MODE>
__global__ __launch_bounds__(256) void gemm_k(const short* __restrict__ W,
                                              const short* __restrict__ Bm,
                                              const float* __restrict__ bias,
                                              const float* __restrict__ xres,
                                              short* __restrict__ qkT,
                                              short* __restrict__ vbuf,
                                              float* __restrict__ outp) {
    constexpr int K = 1024;
    constexpr int NT = K / 64;
    __shared__ short As[2][128 * 64];
    __shared__ short Bs[2][128 * 64];

    int m0 = blockIdx.x * 128, n0 = blockIdx.y * 128, b = blockIdx.z;
    int tid = threadIdx.x;
    int wave = tid >> 6, lane = tid & 63, quad = lane >> 4, l15 = lane & 15;
    int wm = wave >> 1, wn = wave & 1;
    const short* Ab = W + (size_t)m0 * K;
    const short* Bb = Bm + ((size_t)b * Tn + n0) * K;

    float4_t acc[4][4];
    float4_t z = {0.f, 0.f, 0.f, 0.f};
    #pragma unroll
    for (int i = 0; i < 4; i++)
        #pragma unroll
        for (int j = 0; j < 4; j++) acc[i][j] = z;

    int sw = l15 & 7;   // read-side swizzle key

    auto stage = [&](int buf, int k0) {
        #pragma unroll
        for (int r = 0; r < 4; r++) {
            int cid = r * 256 + tid;           // 1024 16B-chunks per array
            int row = cid >> 3, j = cid & 7;
            int ch = j ^ (row & 7);            // swizzled global column
            GLL16(Ab + (size_t)row * K + k0 + ch * 8, &As[buf][cid * 8]);
            GLL16(Bb + (size_t)row * K + k0 + ch * 8, &Bs[buf][cid * 8]);
        }
    };

    // prologue: tiles 0 and 1 in flight; wait for tile 0 only (oldest 8)
    stage(0, 0);
    stage(1, 64);
    __builtin_amdgcn_sched_barrier(0);
    asm volatile("s_waitcnt vmcnt(8)" ::: "memory");
    __builtin_amdgcn_sched_barrier(0);
    __builtin_amdgcn_s_barrier();
    __builtin_amdgcn_sched_barrier(0);

    for (int it = 0; it < NT; ++it) {
        int cur = it & 1;
        #pragma unroll
        for (int kk = 0; kk < 2; kk++) {
            short8 af[4], bfg[4];
            #pragma unroll
            for (int mi = 0; mi < 4; mi++)
                af[mi] = *reinterpret_cast<const short8*>(
                    &As[cur][(wm * 64 + mi * 16 + l15) * 64 + ((4 * kk + quad) ^ sw) * 8]);
            #pragma unroll
            for (int ni = 0; ni < 4; ni++)
                bfg[ni] = *reinterpret_cast<const short8*>(
                    &Bs[cur][(wn * 64 + ni * 16 + l15) * 64 + ((4 * kk + quad) ^ sw) * 8]);
            #pragma unroll
            for (int mi = 0; mi < 4; mi++)
                #pragma unroll
                for (int ni = 0; ni < 4; ni++)
                    acc[mi][ni] = __builtin_amdgcn_mfma_f32_16x16x32_bf16(
                        af[mi], bfg[ni], acc[mi][ni], 0, 0, 0);
        }
        __builtin_amdgcn_sched_barrier(0);
        __builtin_amdgcn_s_barrier();            // all waves done reading buf[cur]
        __builtin_amdgcn_sched_barrier(0);
        if (it + 2 < NT) stage(cur, (it + 2) * 64);   // overwrite freed buffer
        __builtin_amdgcn_sched_barrier(0);
        if (it + 2 < NT) {
            // outstanding: (it+1)'s 8 + (it+2)'s 8; wait oldest 8 -> it+1 landed
            asm volatile("s_waitcnt vmcnt(8)" ::: "memory");
        } else if (it + 1 < NT) {
            asm volatile("s_waitcnt vmcnt(0)" ::: "memory");
        }
        __builtin_amdgcn_sched_barrier(0);
        __builtin_amdgcn_s_barrier();            // cross-wave: it+1 resident
        __builtin_amdgcn_sched_barrier(0);
    }

    if (MODE == 0) {
        #pragma unroll
        for (int mi = 0; mi < 4; mi++) {
            int mrow = m0 + wm * 64 + mi * 16 + quad * 4;
            #pragma unroll
            for (int ni = 0; ni < 4; ni++) {
                int t = n0 + wn * 64 + ni * 16 + l15;
                if (mrow < 2048) {
                    int hh = mrow >> 6, ch = mrow & 63;
                    float sc = (mrow < 1024) ? SCALE_Q : 1.0f;
                    short4_t pk;
                    #pragma unroll
                    for (int r = 0; r < 4; r++)
                        pk[r] = f2bf((acc[mi][ni][r] + bias[mrow + r]) * sc);
                    *reinterpret_cast<short4_t*>(
                        &qkT[(((size_t)b * 32 + hh) * Tn + t) * 64 + ch]) = pk;
                } else {
                    int c = mrow - 2048;
                    #pragma unroll
                    for (int r = 0; r < 4; r++)
                        vbuf[((size_t)b * Cn + c + r) * Tn + t] =
                            f2bf(acc[mi][ni][r] + bias[mrow + r]);
                }
            }
        }
    } else {
        #pragma unroll
        for (int mi = 0; mi < 4; mi++) {
            int mrow = m0 + wm * 64 + mi * 16 + quad * 4;
            #pragma unroll
            for (int ni = 0; ni < 4; ni++) {
                int t = n0 + wn * 64 + ni * 16 + l15;
                #pragma unroll
                for (int r = 0; r < 4; r++) {
                    size_t idx = ((size_t)b * Cn + mrow + r) * Tn + t;
                    outp[idx] = xres[idx] + bias[mrow + r] + acc[mi][ni][r];
                }
            }
        }
    }
}

// ---------------------------------------------------------------- attention
// R5 form restored VERBATIM (proven 76.9 us). 8 waves x 32 q-rows, x32 PV via
// permlane merge, l via ones-MFMA; K/V LDS double-buffered; next tile's
// global loads issued to REGISTERS at the top of the iteration (T14), ds_write
// after compute, ONE __syncthreads per s-tile; setprio around MFMA (T5).
// R6 (halved LDS/HBM traffic) and R7 (0 bank conflicts, raw-barrier pipeline)
// both regressed: staging volume and conflicts are NOT on the critical path,
// and sched_barrier walls defeat the compiler interleave. This is the local
// optimum for this structure.
__global__ __launch_bounds__(512, 4) void attn_k(const short* __restrict__ qkT,
                                                 const short* __restrict__ vbuf,
                                                 short* __restrict__ aT) {
    __shared__ short ks[2][64 * 72];   // [s][ch] +8 pad, double-buffered
    __shared__ short vs[2][64 * 72];   // [ch][s] +8 pad, double-buffered
    int bh = blockIdx.y; int b = bh >> 4, h = bh & 15;
    int t0 = blockIdx.x * 256;
    int tid = threadIdx.x;
    int wave = tid >> 6, lane = tid & 63, quad = lane >> 4, l15 = lane & 15;
    const short* qb = qkT + (((size_t)b * 32 + h) * Tn) * 64;
    const short* kb = qkT + (((size_t)b * 32 + 16 + h) * Tn) * 64;
    const short* vb = vbuf + ((size_t)b * Cn + h * 64) * Tn;
    int tw = t0 + wave * 32;

    // Q B-frags for 2 q-subtiles (global, once)
    short8 qf[2][2];
    #pragma unroll
    for (int tni = 0; tni < 2; tni++)
        #pragma unroll
        for (int kk = 0; kk < 2; kk++)
            qf[tni][kk] = *reinterpret_cast<const short8*>(
                qb + ((size_t)(tw + tni * 16 + l15)) * 64 + kk * 32 + quad * 8);

    short8 ones;
    #pragma unroll
    for (int i = 0; i < 8; i++) ones[i] = (short)0x3F80;   // bf16 1.0

    float4_t z = {0.f, 0.f, 0.f, 0.f};
    float4_t acc[2][4], lacc[2];
    #pragma unroll
    for (int i = 0; i < 2; i++) {
        lacc[i] = z;
        #pragma unroll
        for (int j = 0; j < 4; j++) acc[i][j] = z;
    }

    // staging geometry: each thread owns one 16B chunk per array per tile
    int srow = tid >> 3, soff = (tid & 7) * 8;
    const short* kgp = kb + (size_t)srow * 64 + soff;   // advance 64*64 per tile
    const short* vgp = vb + (size_t)srow * Tn + soff;   // advance 64 per tile
    short* krd = &ks[0][0]; short* kwr = &ks[1][0];
    short* vrd = &vs[0][0]; short* vwr = &vs[1][0];
    int sdst = srow * 72 + soff;

    // prologue: stage tile 0
    {
        uint4 k0v = *reinterpret_cast<const uint4*>(kgp);
        uint4 v0v = *reinterpret_cast<const uint4*>(vgp);
        *reinterpret_cast<uint4*>(&krd[sdst]) = k0v;
        *reinterpret_cast<uint4*>(&vrd[sdst]) = v0v;
    }
    __syncthreads();

    for (int it = 0; it < Tn / 64; ++it) {
        // issue NEXT tile's global loads first — latency hides under compute
        uint4 knx, vnx;
        if (it < Tn / 64 - 1) {
            knx = *reinterpret_cast<const uint4*>(kgp + (size_t)(it + 1) * 64 * 64);
            vnx = *reinterpret_cast<const uint4*>(vgp + (size_t)(it + 1) * 64);
        }

        #pragma unroll
        for (int pr = 0; pr < 2; pr++) {        // 32-s pair block
            uint32_t pk[2][2][2];               // [half][tni][dword], bf16 P
            #pragma unroll
            for (int half = 0; half < 2; half++) {
                int smi = pr * 2 + half;
                // S^T: rows s = smi*16 + quad*4 + r, cols t = tni*16 + l15
                float4_t sa[2] = {z, z};
                __builtin_amdgcn_s_setprio(1);
                #pragma unroll
                for (int kk = 0; kk < 2; kk++) {
                    short8 kf = *reinterpret_cast<const short8*>(
                        &krd[(smi * 16 + l15) * 72 + kk * 32 + quad * 8]);
                    #pragma unroll
                    for (int tni = 0; tni < 2; tni++)
                        sa[tni] = __builtin_amdgcn_mfma_f32_16x16x32_bf16(
                            kf, qf[tni][kk], sa[tni], 0, 0, 0);
                }
                __builtin_amdgcn_s_setprio(0);
                #pragma unroll
                for (int tni = 0; tni < 2; tni++) {
                    float p0 = exp2_fast(sa[tni][0]);
                    float p1 = exp2_fast(sa[tni][1]);
                    float p2 = exp2_fast(sa[tni][2]);
                    float p3 = exp2_fast(sa[tni][3]);
                    pk[half][tni][0] = pack_bf16_trunc(p0, p1);
                    pk[half][tni][1] = pack_bf16_trunc(p2, p3);
                }
            }
            // V B-frags for x32 PV: lane wants V[ch=ci*16+l15][s=pr*32+quad*8..+7]
            short8 vf[4];
            #pragma unroll
            for (int ci = 0; ci < 4; ci++)
                vf[ci] = *reinterpret_cast<const short8*>(
                    &vrd[(ci * 16 + l15) * 72 + pr * 32 + quad * 8]);
            // merge the two 16-s halves into x32 A-layout:
            // (d0,d2) = swap16(swap32(a0,b0)); (d1,d3) = swap16(swap32(a1,b1))
            #pragma unroll
            for (int tni = 0; tni < 2; tni++) {
                uint32_t x0 = pk[0][tni][0], y0 = pk[1][tni][0];
                permswap32(x0, y0); permswap16(x0, y0);   // x0=d0, y0=d2
                uint32_t x1 = pk[0][tni][1], y1 = pk[1][tni][1];
                permswap32(x1, y1); permswap16(x1, y1);   // x1=d1, y1=d3
                uint4 afu = {x0, x1, y0, y1};
                short8 af = *reinterpret_cast<short8*>(&afu);
                __builtin_amdgcn_s_setprio(1);
                lacc[tni] = __builtin_amdgcn_mfma_f32_16x16x32_bf16(
                    af, ones, lacc[tni], 0, 0, 0);
                #pragma unroll
                for (int ci = 0; ci < 4; ci++)
                    acc[tni][ci] = __builtin_amdgcn_mfma_f32_16x16x32_bf16(
                        af, vf[ci], acc[tni][ci], 0, 0, 0);
                __builtin_amdgcn_s_setprio(0);
            }
        }

        // land next tile into the write buffer; one barrier per tile
        if (it < Tn / 64 - 1) {
            *reinterpret_cast<uint4*>(&kwr[sdst]) = knx;
            *reinterpret_cast<uint4*>(&vwr[sdst]) = vnx;
        }
        __syncthreads();
        short* tk = krd; krd = kwr; kwr = tk;
        short* tv = vrd; vrd = vwr; vwr = tv;
    }

    // epilogue: aT[b][t][h*64+ch] = acc / l ; lacc rows are t = quad*4+r,
    // same layout as acc rows — no cross-lane reduction needed.
    #pragma unroll
    for (int tni = 0; tni < 2; tni++) {
        #pragma unroll
        for (int r = 0; r < 4; r++) {
            float rl = 1.0f / lacc[tni][r];
            int t = tw + tni * 16 + quad * 4 + r;
            #pragma unroll
            for (int ci = 0; ci < 4; ci++) {
                int ch = ci * 16 + l15;
                aT[((size_t)b * Tn + t) * Cn + h * 64 + ch] =
                    f2bf(acc[tni][ci][r] * rl);
            }
        }
    }
}

// ---------------------------------------------------------------- launch
extern "C" void kernel_launch(void* const* d_in, const int* in_sizes, int n_in,
                              void* d_out, int out_size, void* d_ws, size_t ws_size,
                              hipStream_t stream) {
    const float* x     = (const float*)d_in[0];
    const float* gs    = (const float*)d_in[1];
    const float* gb    = (const float*)d_in[2];
    const float* qkvw  = (const float*)d_in[3];
    const float* qkvb  = (const float*)d_in[4];
    const float* projw = (const float*)d_in[5];
    const float* projb = (const float*)d_in[6];
    float* out = (float*)d_out;

    char* ws = (char*)d_ws;
    short* wqkv  = (short*)(ws + 0);          //  6 MB  [3072][1024] bf16
    short* wproj = (short*)(ws + 6291456);    //  2 MB  [1024][1024] bf16
    short* xnT   = (short*)(ws + 8388608);    // 16 MB  [b][t][c] bf16
    short* aT    = (short*)(ws + 8388608);    // aliases xnT (dead after QKV GEMM)
    short* qkT   = (short*)(ws + 25165824);   // 32 MB  [b][32][t][64] bf16
    float* gnp   = (float*)(ws + 25165824);   // 8 KB partials (dead before QKV GEMM writes qkT)
    short* vbuf  = (short*)(ws + 58720256);   // 16 MB  [b][c][t] bf16

    cvt_w2<<<dim3(4096), dim3(256), 0, stream>>>(qkvw, projw, wqkv);
    gn_stats<<<dim3(1024), dim3(256), 0, stream>>>(x, gnp);
    gn_apply<<<dim3(1024), dim3(256), 0, stream>>>(x, gs, gb, gnp, xnT);
    gemm_k<0><<<dim3(24, 16, 4), dim3(256), 0, stream>>>(wqkv, xnT, qkvb, nullptr,
                                                         qkT, vbuf, nullptr);
    attn_k<<<dim3(8, 64), dim3(512), 0, stream>>>(qkT, vbuf, aT);
    gemm_k<1><<<dim3(8, 16, 4), dim3(256), 0, stream>>>(wproj, aT, projb, x,
                                                        nullptr, nullptr, out);
}